// Round 9
// baseline (867.717 us; speedup 1.0000x reference)
//
#include <hip/hip_runtime.h>
#include <cmath>

#define NNODES 20000
#define NEDGES 320000

// LDS per-node stride (floats): 576 data + 8 pad.
#define VSTR  584
#define VSTR4 146   // in float4s
#define WSTRIDE 68  // LDS weight row stride (floats)

// ===========================================================================
// Edge path: CSR build (2 atomics/edge) + gather (0 atomics)
// ===========================================================================
__global__ __launch_bounds__(256) void hist_kernel(
    const int* __restrict__ nb, int* __restrict__ counts)
{
    int e = blockIdx.x * 256 + threadIdx.x;
    if (e >= NEDGES) return;
    atomicAdd(counts + nb[e], 1);
}

__global__ __launch_bounds__(1024) void scan_kernel(
    const int* __restrict__ counts, int* __restrict__ base)
{
    __shared__ int part[1024];
    const int t = threadIdx.x;
    int loc[20];
    int s = 0;
#pragma unroll
    for (int j = 0; j < 20; ++j) {
        int idx = t * 20 + j;
        int v = (idx < NNODES) ? counts[idx] : 0;
        loc[j] = s;
        s += v;
    }
    part[t] = s;
    __syncthreads();
    for (int off = 1; off < 1024; off <<= 1) {
        int v = (t >= off) ? part[t - off] : 0;
        __syncthreads();
        part[t] += v;
        __syncthreads();
    }
    int excl = (t > 0) ? part[t - 1] : 0;
#pragma unroll
    for (int j = 0; j < 20; ++j) {
        int idx = t * 20 + j;
        if (idx < NNODES) base[idx] = excl + loc[j];
    }
}

__global__ __launch_bounds__(256) void fill_kernel(
    const float* __restrict__ dist, const int* __restrict__ nb,
    const int* __restrict__ base, int* __restrict__ cursor,
    float* __restrict__ sorted_d)
{
    int e = blockIdx.x * 256 + threadIdx.x;
    if (e >= NEDGES) return;
    int n = nb[e];
    int slot = base[n] + atomicAdd(cursor + n, 1);
    sorted_d[slot] = dist[e];
}

// Per node: phi[32] = sum_e env*rbf, es = sum_e env. No atomics.
__global__ __launch_bounds__(64) void node_phi_kernel(
    const float* __restrict__ sorted_d, const int* __restrict__ base,
    const int* __restrict__ counts,
    float* __restrict__ Phi, float* __restrict__ Env,
    float mu0, float mustep, float beta)
{
    int n = blockIdx.x * 64 + threadIdx.x;
    if (n >= NNODES) return;
    int st = base[n], cnt = counts[n];
    float phi[32];
#pragma unroll
    for (int r = 0; r < 32; ++r) phi[r] = 0.f;
    float es = 0.f;
    for (int j = 0; j < cnt; ++j) {
        float d = sorted_d[st + j];
        float ed = expf(-d);
        float env = (d < 5.0f) ? 0.5f * (cosf(0.62831853071795864769f * d) + 1.0f) : 0.0f;
        es += env;
#pragma unroll
        for (int r = 0; r < 32; ++r) {
            float t = ed - (mu0 + (float)r * mustep);
            phi[r] += env * expf(-beta * t * t);
        }
    }
#pragma unroll
    for (int r = 0; r < 32; ++r) Phi[(size_t)n * 32 + r] = phi[r];
    Env[n] = es;
}

// ===========================================================================
// Node kernel: 8 nodes / 256-thread block, 32 threads/node, 2 out-chans each.
// Weight matrices staged ONE AT A TIME in LDS (rows padded to stride 68).
// Per-thread live state halved vs round-5-measured version to kill spills.
// ===========================================================================
__device__ __forceinline__ void stage_w(const float* __restrict__ W,
                                        float* __restrict__ wbuf, int tid)
{
#pragma unroll
    for (int i = 0; i < 4; ++i) {
        int idx = tid + i * 256;         // float4 id 0..1023
        int row = idx >> 4;              // 16 float4 per 64-float row
        int seg = idx & 15;
        float4 t = reinterpret_cast<const float4*>(W)[idx];
        *reinterpret_cast<float4*>(wbuf + row * WSTRIDE + seg * 4) = t;
    }
}

// y[j][K0+kk] += sum_c wbuf[(q+32j)*68+c] * vb[(K0+kk)*64+c], j=0,1
template <int K0, int NK>
__device__ __forceinline__ void mix_phase(const float* __restrict__ vb,
    const float* __restrict__ wbuf, int q, float (&y)[2][9])
{
#pragma unroll
    for (int c4 = 0; c4 < 16; ++c4) {
        float4 v[NK];
#pragma unroll
        for (int kk = 0; kk < NK; ++kk)
            v[kk] = *reinterpret_cast<const float4*>(vb + (K0 + kk) * 64 + c4 * 4);
#pragma unroll
        for (int j = 0; j < 2; ++j) {
            float4 w = *reinterpret_cast<const float4*>(wbuf + (q + 32 * j) * WSTRIDE + c4 * 4);
#pragma unroll
            for (int kk = 0; kk < NK; ++kk)
                y[j][K0 + kk] += w.x * v[kk].x + w.y * v[kk].y + w.z * v[kk].z + w.w * v[kk].w;
        }
    }
}

__global__ __launch_bounds__(256, 3) void node_kernel(
    const float* __restrict__ X,
    const float* __restrict__ Phi, const float* __restrict__ Env,
    const float* __restrict__ WIpre,  const float* __restrict__ WApre,  const float* __restrict__ WSpre,
    const float* __restrict__ WIpost, const float* __restrict__ WApost, const float* __restrict__ WSpost,
    const float* __restrict__ Wdist, const float* __restrict__ bdist,
    float* __restrict__ out)
{
    __shared__ __align__(16) float vals[8 * VSTR];      // 18.7 KB
    __shared__ __align__(16) float wbuf[64 * WSTRIDE];  // 17.4 KB
    __shared__ __align__(16) float phiS[8 * 36];        // 1.2 KB
    __shared__ float envS[8];

    const int tid = threadIdx.x;
    const int ln  = tid >> 5;          // node in block (0..7)
    const int q   = tid & 31;          // lane in node group
    const int node0 = blockIdx.x * 8;
    float* vb = &vals[ln * VSTR];

    // ---- loads: X tile, phi, env; stage pre-iso weights ----
    {
        const float4* src = reinterpret_cast<const float4*>(X + (size_t)node0 * 576);
        float4* dst = reinterpret_cast<float4*>(vals);
        for (int i = tid; i < 1152; i += 256) dst[(i / 144) * VSTR4 + (i % 144)] = src[i];
    }
    phiS[(tid >> 5) * 36 + (tid & 31)] = Phi[(size_t)(node0 + (tid >> 5)) * 32 + (tid & 31)];
    if (tid < 8) envS[tid] = Env[node0 + tid];
    stage_w(WIpre, wbuf, tid);
    __syncthreads();                                    // (1)

    // ---- normalize + decompose (2 channels/thread) ----
    float comps[2][9];
#pragma unroll
    for (int h = 0; h < 2; ++h) {
        const int c = q + 32 * h;
        const float* x = vb + c * 9;
        float v[9];
#pragma unroll
        for (int k = 0; k < 9; ++k) v[k] = x[k];
        float fr = 0.f;
#pragma unroll
        for (int k = 0; k < 9; ++k) fr += v[k] * v[k];
        float s = 1.0f / (fr + 1.0f);
#pragma unroll
        for (int k = 0; k < 9; ++k) v[k] *= s;
        float dm = (v[0] + v[4] + v[8]) * (1.0f / 3.0f);
        comps[h][0] = dm;
        comps[h][1] = 0.5f * (v[1] - v[3]);
        comps[h][2] = 0.5f * (v[2] - v[6]);
        comps[h][3] = 0.5f * (v[5] - v[7]);
        comps[h][4] = v[0] - dm;
        comps[h][5] = 0.5f * (v[1] + v[3]);
        comps[h][6] = 0.5f * (v[2] + v[6]);
        comps[h][7] = v[4] - dm;
        comps[h][8] = 0.5f * (v[5] + v[7]);
    }
    __syncthreads();                                    // (2) raw reads done
#pragma unroll
    for (int h = 0; h < 2; ++h) {
        const int c = q + 32 * h;
#pragma unroll
        for (int k = 0; k < 9; ++k) vb[k * 64 + c] = comps[h][k];
    }
    __syncthreads();                                    // (3) comps visible

    // ---- pre mixing: I, A, S sub-phases with one LDS-staged matrix each ----
    float y[2][9];
#pragma unroll
    for (int j = 0; j < 2; ++j)
#pragma unroll
        for (int k = 0; k < 9; ++k) y[j][k] = 0.f;

    mix_phase<0, 1>(vb, wbuf, q, y);
    __syncthreads();                                    // (4) done reading WIpre
    stage_w(WApre, wbuf, tid);
    __syncthreads();                                    // (5)
    mix_phase<1, 3>(vb, wbuf, q, y);
    __syncthreads();                                    // (6)
    stage_w(WSpre, wbuf, tid);
    __syncthreads();                                    // (7)
    mix_phase<4, 5>(vb, wbuf, q, y);

    // ---- edge coefficient sums (phiS LDS broadcast + Wdist via L1) ----
    float fIv[2], fAv[2], fSv[2];
    {
        const float* ph = &phiS[ln * 36];
        float es = envS[ln];
#pragma unroll
        for (int h = 0; h < 2; ++h) {
            const int c = q + 32 * h;
            float accI = 0.f, accA = 0.f, accS = 0.f;
            const float4* wI = reinterpret_cast<const float4*>(Wdist + (size_t)c * 32);
            const float4* wA = reinterpret_cast<const float4*>(Wdist + (size_t)(64 + c) * 32);
            const float4* wS = reinterpret_cast<const float4*>(Wdist + (size_t)(128 + c) * 32);
#pragma unroll
            for (int r = 0; r < 8; ++r) {
                float4 p = *reinterpret_cast<const float4*>(ph + r * 4);
                float4 a = wI[r]; accI += p.x*a.x + p.y*a.y + p.z*a.z + p.w*a.w;
                float4 b = wA[r]; accA += p.x*b.x + p.y*b.y + p.z*b.z + p.w*b.w;
                float4 cc= wS[r]; accS += p.x*cc.x + p.y*cc.y + p.z*cc.z + p.w*cc.w;
            }
            fIv[h] = accI + es * bdist[c];
            fAv[h] = accA + es * bdist[64 + c];
            fSv[h] = accS + es * bdist[128 + c];
        }
    }

    // ---- per-channel tensor algebra (reads comps back from LDS) ----
    float yn2[2][9];
#pragma unroll
    for (int h = 0; h < 2; ++h) {
        const int c = q + 32 * h;
        float cc[9];
#pragma unroll
        for (int k = 0; k < 9; ++k) cc[k] = vb[k * 64 + c];
        float fi = fIv[h], fa = fAv[h], fs = fSv[h];
        float m[9];
        m[0] =  fi * cc[0] + fs * cc[4];
        m[1] =  fa * cc[1] + fs * cc[5];
        m[2] =  fa * cc[2] + fs * cc[6];
        m[3] = -fa * cc[1] + fs * cc[5];
        m[4] =  fi * cc[0] + fs * cc[7];
        m[5] =  fa * cc[3] + fs * cc[8];
        m[6] = -fa * cc[2] + fs * cc[6];
        m[7] = -fa * cc[3] + fs * cc[8];
        m[8] =  fi * cc[0] - fs * (cc[4] + cc[7]);
        float yf[9];
        yf[0] =  y[h][0] + y[h][4];
        yf[1] =  y[h][1] + y[h][5];
        yf[2] =  y[h][2] + y[h][6];
        yf[3] = -y[h][1] + y[h][5];
        yf[4] =  y[h][0] + y[h][7];
        yf[5] =  y[h][3] + y[h][8];
        yf[6] = -y[h][2] + y[h][6];
        yf[7] = -y[h][3] + y[h][8];
        yf[8] =  y[h][0] - y[h][4] - y[h][7];
        float t[9];
#pragma unroll
        for (int i = 0; i < 3; ++i)
#pragma unroll
            for (int j = 0; j < 3; ++j) {
                float acc = 0.f;
#pragma unroll
                for (int k = 0; k < 3; ++k)
                    acc += yf[i*3+k] * m[k*3+j] + m[i*3+k] * yf[k*3+j];
                t[i*3+j] = acc;
            }
        float nr = 0.f;
#pragma unroll
        for (int k = 0; k < 9; ++k) { float u = t[k] + 1.0f; nr += u * u; }
        float inv = 1.0f / nr;
#pragma unroll
        for (int k = 0; k < 9; ++k) t[k] *= inv;
        float dm = (t[0] + t[4] + t[8]) * (1.0f / 3.0f);
        yn2[h][0] = dm;
        yn2[h][1] = 0.5f * (t[1] - t[3]);
        yn2[h][2] = 0.5f * (t[2] - t[6]);
        yn2[h][3] = 0.5f * (t[5] - t[7]);
        yn2[h][4] = t[0] - dm;
        yn2[h][5] = 0.5f * (t[1] + t[3]);
        yn2[h][6] = 0.5f * (t[2] + t[6]);
        yn2[h][7] = t[4] - dm;
        yn2[h][8] = 0.5f * (t[5] + t[7]);
    }
    __syncthreads();                                    // (8) comps + WSpre reads done

#pragma unroll
    for (int h = 0; h < 2; ++h) {
        const int c = q + 32 * h;
#pragma unroll
        for (int k = 0; k < 9; ++k) vb[k * 64 + c] = yn2[h][k];
    }
    stage_w(WIpost, wbuf, tid);
    __syncthreads();                                    // (9)

    // ---- post mixing ----
    float z[2][9];
#pragma unroll
    for (int j = 0; j < 2; ++j)
#pragma unroll
        for (int k = 0; k < 9; ++k) z[j][k] = 0.f;

    mix_phase<0, 1>(vb, wbuf, q, z);
    __syncthreads();                                    // (10)
    stage_w(WApost, wbuf, tid);
    __syncthreads();                                    // (11)
    mix_phase<1, 3>(vb, wbuf, q, z);
    __syncthreads();                                    // (12)
    stage_w(WSpost, wbuf, tid);
    __syncthreads();                                    // (13)
    mix_phase<4, 5>(vb, wbuf, q, z);
    __syncthreads();                                    // (14) done reading comps

    // ---- reconstruct, out = Y + Y@Y, stage contiguous per node ----
#pragma unroll
    for (int h = 0; h < 2; ++h) {
        const int o = q + 32 * h;
        float w[9];
        w[0] =  z[h][0] + z[h][4];
        w[1] =  z[h][1] + z[h][5];
        w[2] =  z[h][2] + z[h][6];
        w[3] = -z[h][1] + z[h][5];
        w[4] =  z[h][0] + z[h][7];
        w[5] =  z[h][3] + z[h][8];
        w[6] = -z[h][2] + z[h][6];
        w[7] = -z[h][3] + z[h][8];
        w[8] =  z[h][0] - z[h][4] - z[h][7];
#pragma unroll
        for (int i = 0; i < 3; ++i)
#pragma unroll
            for (int j = 0; j < 3; ++j) {
                float acc = w[i*3+j];
#pragma unroll
                for (int k = 0; k < 3; ++k) acc += w[i*3+k] * w[k*3+j];
                vb[o * 9 + i*3+j] = acc;
            }
    }
    __syncthreads();                                    // (15)
    {
        float4* dst = reinterpret_cast<float4*>(out + (size_t)node0 * 576);
        const float4* srcv = reinterpret_cast<const float4*>(vals);
        for (int i = tid; i < 1152; i += 256) dst[i] = srcv[(i / 144) * VSTR4 + (i % 144)];
    }
}

// ===========================================================================
extern "C" void kernel_launch(void* const* d_in, const int* in_sizes, int n_in,
                              void* d_out, int out_size, void* d_ws, size_t ws_size,
                              hipStream_t stream)
{
    const float* X      = (const float*)d_in[0];
    const float* dist   = (const float*)d_in[1];
    const int*   nb     = (const int*)d_in[2];
    const float* WIpre  = (const float*)d_in[3];
    const float* WApre  = (const float*)d_in[4];
    const float* WSpre  = (const float*)d_in[5];
    const float* WIpost = (const float*)d_in[6];
    const float* WApost = (const float*)d_in[7];
    const float* WSpost = (const float*)d_in[8];
    const float* Wdist  = (const float*)d_in[9];
    const float* bdist  = (const float*)d_in[10];
    float* out = (float*)d_out;

    // workspace layout (floats/ints)
    float* Phi      = (float*)d_ws;                         // 20000*32 f
    float* Env      = Phi + (size_t)NNODES * 32;            // 20000 f
    float* sorted_d = Env + NNODES;                         // 320000 f
    int*   counts   = (int*)(sorted_d + NEDGES);            // 20000 i
    int*   cursor   = counts + NNODES;                      // 20000 i
    int*   base     = cursor + NNODES;                      // 20000 i

    // zero counts+cursor only (contiguous)
    hipMemsetAsync(counts, 0, 2 * (size_t)NNODES * sizeof(int), stream);

    double em5   = std::exp(-5.0);
    double step  = (1.0 - em5) / 31.0;
    double fac   = (2.0 / 32.0) * (1.0 - em5);
    double betad = 1.0 / (fac * fac);

    hist_kernel<<<(NEDGES + 255) / 256, 256, 0, stream>>>(nb, counts);
    scan_kernel<<<1, 1024, 0, stream>>>(counts, base);
    fill_kernel<<<(NEDGES + 255) / 256, 256, 0, stream>>>(dist, nb, base, cursor, sorted_d);
    node_phi_kernel<<<(NNODES + 63) / 64, 64, 0, stream>>>(
        sorted_d, base, counts, Phi, Env, (float)em5, (float)step, (float)betad);
    node_kernel<<<NNODES / 8, 256, 0, stream>>>(
        X, Phi, Env, WIpre, WApre, WSpre, WIpost, WApost, WSpost, Wdist, bdist, out);
}

// Round 10
// 456.143 us; speedup vs baseline: 1.9023x; 1.9023x over previous
//
#include <hip/hip_runtime.h>
#include <cmath>

#define NNODES 20000
#define NEDGES 320000

// LDS per-node stride (floats): 576 data + 8 pad.
#define VSTR  584
#define VSTR4 146   // in float4s
#define WSTRIDE 68  // LDS weight row stride (floats)

// ===========================================================================
// Edge path: CSR build (2 atomics/edge) + gather (0 atomics)
// ===========================================================================
__global__ __launch_bounds__(256) void hist_kernel(
    const int* __restrict__ nb, int* __restrict__ counts)
{
    int e = blockIdx.x * 256 + threadIdx.x;
    if (e >= NEDGES) return;
    atomicAdd(counts + nb[e], 1);
}

__global__ __launch_bounds__(1024) void scan_kernel(
    const int* __restrict__ counts, int* __restrict__ base)
{
    __shared__ int part[1024];
    const int t = threadIdx.x;
    int loc[20];
    int s = 0;
#pragma unroll
    for (int j = 0; j < 20; ++j) {
        int idx = t * 20 + j;
        int v = (idx < NNODES) ? counts[idx] : 0;
        loc[j] = s;
        s += v;
    }
    part[t] = s;
    __syncthreads();
    for (int off = 1; off < 1024; off <<= 1) {
        int v = (t >= off) ? part[t - off] : 0;
        __syncthreads();
        part[t] += v;
        __syncthreads();
    }
    int excl = (t > 0) ? part[t - 1] : 0;
#pragma unroll
    for (int j = 0; j < 20; ++j) {
        int idx = t * 20 + j;
        if (idx < NNODES) base[idx] = excl + loc[j];
    }
}

__global__ __launch_bounds__(256) void fill_kernel(
    const float* __restrict__ dist, const int* __restrict__ nb,
    const int* __restrict__ base, int* __restrict__ cursor,
    float* __restrict__ sorted_d)
{
    int e = blockIdx.x * 256 + threadIdx.x;
    if (e >= NEDGES) return;
    int n = nb[e];
    int slot = base[n] + atomicAdd(cursor + n, 1);
    sorted_d[slot] = dist[e];
}

// Per node: phi[32] = sum_e env*rbf, es = sum_e env. No atomics.
__global__ __launch_bounds__(64) void node_phi_kernel(
    const float* __restrict__ sorted_d, const int* __restrict__ base,
    const int* __restrict__ counts,
    float* __restrict__ Phi, float* __restrict__ Env,
    float mu0, float mustep, float beta)
{
    int n = blockIdx.x * 64 + threadIdx.x;
    if (n >= NNODES) return;
    int st = base[n], cnt = counts[n];
    float phi[32];
#pragma unroll
    for (int r = 0; r < 32; ++r) phi[r] = 0.f;
    float es = 0.f;
    for (int j = 0; j < cnt; ++j) {
        float d = sorted_d[st + j];
        float ed = expf(-d);
        float env = (d < 5.0f) ? 0.5f * (cosf(0.62831853071795864769f * d) + 1.0f) : 0.0f;
        es += env;
#pragma unroll
        for (int r = 0; r < 32; ++r) {
            float t = ed - (mu0 + (float)r * mustep);
            phi[r] += env * expf(-beta * t * t);
        }
    }
#pragma unroll
    for (int r = 0; r < 32; ++r) Phi[(size_t)n * 32 + r] = phi[r];
    Env[n] = es;
}

// ===========================================================================
// Node kernel: 8 nodes / 256-thread block, 32 threads/node, 2 out-chans each.
// Weight matrices staged ONE AT A TIME in LDS (rows padded to stride 68).
// NOTE: no min-occupancy in __launch_bounds__ — forcing 3 waves/EU (r9)
// pushed VGPR under 128, demoted the mix accumulators to scratch, and
// generated 2.28 GB of spill traffic (measured). Let the allocator float.
// ===========================================================================
__device__ __forceinline__ void stage_w(const float* __restrict__ W,
                                        float* __restrict__ wbuf, int tid)
{
#pragma unroll
    for (int i = 0; i < 4; ++i) {
        int idx = tid + i * 256;         // float4 id 0..1023
        int row = idx >> 4;              // 16 float4 per 64-float row
        int seg = idx & 15;
        float4 t = reinterpret_cast<const float4*>(W)[idx];
        *reinterpret_cast<float4*>(wbuf + row * WSTRIDE + seg * 4) = t;
    }
}

// y[j][K0+kk] += sum_c wbuf[(q+32j)*68+c] * vb[(K0+kk)*64+c], j=0,1
template <int K0, int NK>
__device__ __forceinline__ void mix_phase(const float* __restrict__ vb,
    const float* __restrict__ wbuf, int q, float (&y)[2][9])
{
#pragma unroll
    for (int c4 = 0; c4 < 16; ++c4) {
        float4 v[NK];
#pragma unroll
        for (int kk = 0; kk < NK; ++kk)
            v[kk] = *reinterpret_cast<const float4*>(vb + (K0 + kk) * 64 + c4 * 4);
#pragma unroll
        for (int j = 0; j < 2; ++j) {
            float4 w = *reinterpret_cast<const float4*>(wbuf + (q + 32 * j) * WSTRIDE + c4 * 4);
#pragma unroll
            for (int kk = 0; kk < NK; ++kk)
                y[j][K0 + kk] += w.x * v[kk].x + w.y * v[kk].y + w.z * v[kk].z + w.w * v[kk].w;
        }
    }
}

__global__ __launch_bounds__(256) void node_kernel(
    const float* __restrict__ X,
    const float* __restrict__ Phi, const float* __restrict__ Env,
    const float* __restrict__ WIpre,  const float* __restrict__ WApre,  const float* __restrict__ WSpre,
    const float* __restrict__ WIpost, const float* __restrict__ WApost, const float* __restrict__ WSpost,
    const float* __restrict__ Wdist, const float* __restrict__ bdist,
    float* __restrict__ out)
{
    __shared__ __align__(16) float vals[8 * VSTR];      // 18.7 KB
    __shared__ __align__(16) float wbuf[64 * WSTRIDE];  // 17.4 KB
    __shared__ __align__(16) float phiS[8 * 36];        // 1.2 KB
    __shared__ float envS[8];

    const int tid = threadIdx.x;
    const int ln  = tid >> 5;          // node in block (0..7)
    const int q   = tid & 31;          // lane in node group
    const int node0 = blockIdx.x * 8;
    float* vb = &vals[ln * VSTR];

    // ---- loads: X tile, phi, env; stage pre-iso weights ----
    {
        const float4* src = reinterpret_cast<const float4*>(X + (size_t)node0 * 576);
        float4* dst = reinterpret_cast<float4*>(vals);
        for (int i = tid; i < 1152; i += 256) dst[(i / 144) * VSTR4 + (i % 144)] = src[i];
    }
    phiS[(tid >> 5) * 36 + (tid & 31)] = Phi[(size_t)(node0 + (tid >> 5)) * 32 + (tid & 31)];
    if (tid < 8) envS[tid] = Env[node0 + tid];
    stage_w(WIpre, wbuf, tid);
    __syncthreads();                                    // (1)

    // ---- normalize + decompose (2 channels/thread) ----
    float comps[2][9];
#pragma unroll
    for (int h = 0; h < 2; ++h) {
        const int c = q + 32 * h;
        const float* x = vb + c * 9;
        float v[9];
#pragma unroll
        for (int k = 0; k < 9; ++k) v[k] = x[k];
        float fr = 0.f;
#pragma unroll
        for (int k = 0; k < 9; ++k) fr += v[k] * v[k];
        float s = 1.0f / (fr + 1.0f);
#pragma unroll
        for (int k = 0; k < 9; ++k) v[k] *= s;
        float dm = (v[0] + v[4] + v[8]) * (1.0f / 3.0f);
        comps[h][0] = dm;
        comps[h][1] = 0.5f * (v[1] - v[3]);
        comps[h][2] = 0.5f * (v[2] - v[6]);
        comps[h][3] = 0.5f * (v[5] - v[7]);
        comps[h][4] = v[0] - dm;
        comps[h][5] = 0.5f * (v[1] + v[3]);
        comps[h][6] = 0.5f * (v[2] + v[6]);
        comps[h][7] = v[4] - dm;
        comps[h][8] = 0.5f * (v[5] + v[7]);
    }
    __syncthreads();                                    // (2) raw reads done
#pragma unroll
    for (int h = 0; h < 2; ++h) {
        const int c = q + 32 * h;
#pragma unroll
        for (int k = 0; k < 9; ++k) vb[k * 64 + c] = comps[h][k];
    }
    __syncthreads();                                    // (3) comps visible

    // ---- pre mixing: I, A, S sub-phases with one LDS-staged matrix each ----
    float y[2][9];
#pragma unroll
    for (int j = 0; j < 2; ++j)
#pragma unroll
        for (int k = 0; k < 9; ++k) y[j][k] = 0.f;

    mix_phase<0, 1>(vb, wbuf, q, y);
    __syncthreads();                                    // (4) done reading WIpre
    stage_w(WApre, wbuf, tid);
    __syncthreads();                                    // (5)
    mix_phase<1, 3>(vb, wbuf, q, y);
    __syncthreads();                                    // (6)
    stage_w(WSpre, wbuf, tid);
    __syncthreads();                                    // (7)
    mix_phase<4, 5>(vb, wbuf, q, y);

    // ---- edge coefficient sums (phiS LDS broadcast + Wdist via L1) ----
    float fIv[2], fAv[2], fSv[2];
    {
        const float* ph = &phiS[ln * 36];
        float es = envS[ln];
#pragma unroll
        for (int h = 0; h < 2; ++h) {
            const int c = q + 32 * h;
            float accI = 0.f, accA = 0.f, accS = 0.f;
            const float4* wI = reinterpret_cast<const float4*>(Wdist + (size_t)c * 32);
            const float4* wA = reinterpret_cast<const float4*>(Wdist + (size_t)(64 + c) * 32);
            const float4* wS = reinterpret_cast<const float4*>(Wdist + (size_t)(128 + c) * 32);
#pragma unroll
            for (int r = 0; r < 8; ++r) {
                float4 p = *reinterpret_cast<const float4*>(ph + r * 4);
                float4 a = wI[r]; accI += p.x*a.x + p.y*a.y + p.z*a.z + p.w*a.w;
                float4 b = wA[r]; accA += p.x*b.x + p.y*b.y + p.z*b.z + p.w*b.w;
                float4 cc= wS[r]; accS += p.x*cc.x + p.y*cc.y + p.z*cc.z + p.w*cc.w;
            }
            fIv[h] = accI + es * bdist[c];
            fAv[h] = accA + es * bdist[64 + c];
            fSv[h] = accS + es * bdist[128 + c];
        }
    }

    // ---- per-channel tensor algebra (reads comps back from LDS) ----
    float yn2[2][9];
#pragma unroll
    for (int h = 0; h < 2; ++h) {
        const int c = q + 32 * h;
        float cc[9];
#pragma unroll
        for (int k = 0; k < 9; ++k) cc[k] = vb[k * 64 + c];
        float fi = fIv[h], fa = fAv[h], fs = fSv[h];
        float m[9];
        m[0] =  fi * cc[0] + fs * cc[4];
        m[1] =  fa * cc[1] + fs * cc[5];
        m[2] =  fa * cc[2] + fs * cc[6];
        m[3] = -fa * cc[1] + fs * cc[5];
        m[4] =  fi * cc[0] + fs * cc[7];
        m[5] =  fa * cc[3] + fs * cc[8];
        m[6] = -fa * cc[2] + fs * cc[6];
        m[7] = -fa * cc[3] + fs * cc[8];
        m[8] =  fi * cc[0] - fs * (cc[4] + cc[7]);
        float yf[9];
        yf[0] =  y[h][0] + y[h][4];
        yf[1] =  y[h][1] + y[h][5];
        yf[2] =  y[h][2] + y[h][6];
        yf[3] = -y[h][1] + y[h][5];
        yf[4] =  y[h][0] + y[h][7];
        yf[5] =  y[h][3] + y[h][8];
        yf[6] = -y[h][2] + y[h][6];
        yf[7] = -y[h][3] + y[h][8];
        yf[8] =  y[h][0] - y[h][4] - y[h][7];
        float t[9];
#pragma unroll
        for (int i = 0; i < 3; ++i)
#pragma unroll
            for (int j = 0; j < 3; ++j) {
                float acc = 0.f;
#pragma unroll
                for (int k = 0; k < 3; ++k)
                    acc += yf[i*3+k] * m[k*3+j] + m[i*3+k] * yf[k*3+j];
                t[i*3+j] = acc;
            }
        float nr = 0.f;
#pragma unroll
        for (int k = 0; k < 9; ++k) { float u = t[k] + 1.0f; nr += u * u; }
        float inv = 1.0f / nr;
#pragma unroll
        for (int k = 0; k < 9; ++k) t[k] *= inv;
        float dm = (t[0] + t[4] + t[8]) * (1.0f / 3.0f);
        yn2[h][0] = dm;
        yn2[h][1] = 0.5f * (t[1] - t[3]);
        yn2[h][2] = 0.5f * (t[2] - t[6]);
        yn2[h][3] = 0.5f * (t[5] - t[7]);
        yn2[h][4] = t[0] - dm;
        yn2[h][5] = 0.5f * (t[1] + t[3]);
        yn2[h][6] = 0.5f * (t[2] + t[6]);
        yn2[h][7] = t[4] - dm;
        yn2[h][8] = 0.5f * (t[5] + t[7]);
    }
    __syncthreads();                                    // (8) comps + WSpre reads done

#pragma unroll
    for (int h = 0; h < 2; ++h) {
        const int c = q + 32 * h;
#pragma unroll
        for (int k = 0; k < 9; ++k) vb[k * 64 + c] = yn2[h][k];
    }
    stage_w(WIpost, wbuf, tid);
    __syncthreads();                                    // (9)

    // ---- post mixing ----
    float z[2][9];
#pragma unroll
    for (int j = 0; j < 2; ++j)
#pragma unroll
        for (int k = 0; k < 9; ++k) z[j][k] = 0.f;

    mix_phase<0, 1>(vb, wbuf, q, z);
    __syncthreads();                                    // (10)
    stage_w(WApost, wbuf, tid);
    __syncthreads();                                    // (11)
    mix_phase<1, 3>(vb, wbuf, q, z);
    __syncthreads();                                    // (12)
    stage_w(WSpost, wbuf, tid);
    __syncthreads();                                    // (13)
    mix_phase<4, 5>(vb, wbuf, q, z);
    __syncthreads();                                    // (14) done reading comps

    // ---- reconstruct, out = Y + Y@Y, stage contiguous per node ----
#pragma unroll
    for (int h = 0; h < 2; ++h) {
        const int o = q + 32 * h;
        float w[9];
        w[0] =  z[h][0] + z[h][4];
        w[1] =  z[h][1] + z[h][5];
        w[2] =  z[h][2] + z[h][6];
        w[3] = -z[h][1] + z[h][5];
        w[4] =  z[h][0] + z[h][7];
        w[5] =  z[h][3] + z[h][8];
        w[6] = -z[h][2] + z[h][6];
        w[7] = -z[h][3] + z[h][8];
        w[8] =  z[h][0] - z[h][4] - z[h][7];
#pragma unroll
        for (int i = 0; i < 3; ++i)
#pragma unroll
            for (int j = 0; j < 3; ++j) {
                float acc = w[i*3+j];
#pragma unroll
                for (int k = 0; k < 3; ++k) acc += w[i*3+k] * w[k*3+j];
                vb[o * 9 + i*3+j] = acc;
            }
    }
    __syncthreads();                                    // (15)
    {
        float4* dst = reinterpret_cast<float4*>(out + (size_t)node0 * 576);
        const float4* srcv = reinterpret_cast<const float4*>(vals);
        for (int i = tid; i < 1152; i += 256) dst[i] = srcv[(i / 144) * VSTR4 + (i % 144)];
    }
}

// ===========================================================================
extern "C" void kernel_launch(void* const* d_in, const int* in_sizes, int n_in,
                              void* d_out, int out_size, void* d_ws, size_t ws_size,
                              hipStream_t stream)
{
    const float* X      = (const float*)d_in[0];
    const float* dist   = (const float*)d_in[1];
    const int*   nb     = (const int*)d_in[2];
    const float* WIpre  = (const float*)d_in[3];
    const float* WApre  = (const float*)d_in[4];
    const float* WSpre  = (const float*)d_in[5];
    const float* WIpost = (const float*)d_in[6];
    const float* WApost = (const float*)d_in[7];
    const float* WSpost = (const float*)d_in[8];
    const float* Wdist  = (const float*)d_in[9];
    const float* bdist  = (const float*)d_in[10];
    float* out = (float*)d_out;

    // workspace layout (floats/ints)
    float* Phi      = (float*)d_ws;                         // 20000*32 f
    float* Env      = Phi + (size_t)NNODES * 32;            // 20000 f
    float* sorted_d = Env + NNODES;                         // 320000 f
    int*   counts   = (int*)(sorted_d + NEDGES);            // 20000 i
    int*   cursor   = counts + NNODES;                      // 20000 i
    int*   base     = cursor + NNODES;                      // 20000 i

    // zero counts+cursor only (contiguous)
    hipMemsetAsync(counts, 0, 2 * (size_t)NNODES * sizeof(int), stream);

    double em5   = std::exp(-5.0);
    double step  = (1.0 - em5) / 31.0;
    double fac   = (2.0 / 32.0) * (1.0 - em5);
    double betad = 1.0 / (fac * fac);

    hist_kernel<<<(NEDGES + 255) / 256, 256, 0, stream>>>(nb, counts);
    scan_kernel<<<1, 1024, 0, stream>>>(counts, base);
    fill_kernel<<<(NEDGES + 255) / 256, 256, 0, stream>>>(dist, nb, base, cursor, sorted_d);
    node_phi_kernel<<<(NNODES + 63) / 64, 64, 0, stream>>>(
        sorted_d, base, counts, Phi, Env, (float)em5, (float)step, (float)betad);
    node_kernel<<<NNODES / 8, 256, 0, stream>>>(
        X, Phi, Env, WIpre, WApre, WSpre, WIpost, WApost, WSpost, Wdist, bdist, out);
}